// Round 1
// baseline (843.861 us; speedup 1.0000x reference)
//
#include <hip/hip_runtime.h>
#include <math.h>

// Masked similar-user attention: out[b,s,d] = softmax_u(mask? -1e9 : cu[b]·sue[b,s,u]) · sue[b,s,u,d] + cie[b,s,d]
// One wave (64 lanes) per (b,s) tile. sue tile (50x32 fp32) held in registers
// between score phase and weighted-sum phase -> sue read from HBM exactly once.
// Lane layout: lane l, chunk j holds float4 at tile element j*256+4l
//   => u = 8j + (l>>3), d = 4*(l&7). j=0..6 covers u in [0,56); u>=50 padded (-inf).

#define NEG_INF_F (-1e9f)

constexpr int B = 512, S = 200, U = 50, D = 32;
constexpr int TILES = B * S;                      // 102400
constexpr int TILE_F4 = U * D / 4;                // 400 float4 per tile
constexpr int SUE_F4 = TILES * TILE_F4;           // 40,960,000 float4 total

__global__ __launch_bounds__(256) void DIB_69861938037647_kernel(
    const float* __restrict__ cu,    // [B, D]
    const float* __restrict__ sue,   // [B, S, U, D]
    const float* __restrict__ cie,   // [B, S, D]
    const int*   __restrict__ mask,  // [B, S, U]  nonzero = masked out
    float* __restrict__ out)         // [B, S, D]
{
    const int lane = threadIdx.x & 63;
    const int wave = threadIdx.x >> 6;
    const int tile = blockIdx.x * 4 + wave;       // = b*S + s

    const int g  = lane >> 3;                     // u subgroup 0..7
    const int d0 = (lane & 7) * 4;                // d offset 0,4,...,28

    // ---- stage sue tile into registers (coalesced 1KiB/wave float4 loads) ----
    const float4* sue4 = (const float4*)sue;
    float4 v[7];
    const int base4 = tile * TILE_F4;
    #pragma unroll
    for (int j = 0; j < 7; ++j) {
        int gi = base4 + j * 64 + lane;
        gi = min(gi, SUE_F4 - 1);                 // clamp padding over-read (last tile only)
        v[j] = sue4[gi];
    }

    // ---- user-embedding fragment (broadcast via cache) ----
    const int b = tile / S;
    const float4 c4 = *(const float4*)(cu + b * D + d0);

    // ---- scores: per-lane partial dot, reduce over d via xor 1/2/4 ----
    float sc[7];
    #pragma unroll
    for (int j = 0; j < 7; ++j) {
        float p = v[j].x * c4.x + v[j].y * c4.y + v[j].z * c4.z + v[j].w * c4.w;
        p += __shfl_xor(p, 1);
        p += __shfl_xor(p, 2);
        p += __shfl_xor(p, 4);
        sc[j] = p;                                // full dot for u = 8j+g, all 8 lanes of group
    }

    // ---- mask (reference uses finite -1e9; padding u>=50 uses true -inf) ----
    const int mrow = tile * U;
    #pragma unroll
    for (int j = 0; j < 7; ++j) {
        const int u = j * 8 + g;
        if (u < U) {
            if (mask[mrow + u]) sc[j] = NEG_INF_F;
        } else {
            sc[j] = -INFINITY;
        }
    }

    // ---- softmax over u: reduce across the 8 u-subgroups via xor 8/16/32 ----
    float m = sc[0];
    #pragma unroll
    for (int j = 1; j < 7; ++j) m = fmaxf(m, sc[j]);
    m = fmaxf(m, __shfl_xor(m, 8));
    m = fmaxf(m, __shfl_xor(m, 16));
    m = fmaxf(m, __shfl_xor(m, 32));

    float e[7];
    float tsum = 0.f;
    #pragma unroll
    for (int j = 0; j < 7; ++j) {
        e[j] = __expf(sc[j] - m);                 // -inf -> 0; all-masked row -> uniform 1/50
        tsum += e[j];
    }
    tsum += __shfl_xor(tsum, 8);
    tsum += __shfl_xor(tsum, 16);
    tsum += __shfl_xor(tsum, 32);
    const float inv = 1.0f / tsum;

    // ---- weighted sum over u (values still in registers) ----
    float4 o = make_float4(0.f, 0.f, 0.f, 0.f);
    #pragma unroll
    for (int j = 0; j < 7; ++j) {
        const float a = e[j] * inv;
        o.x += a * v[j].x; o.y += a * v[j].y; o.z += a * v[j].z; o.w += a * v[j].w;
    }
    #pragma unroll
    for (int msk = 8; msk <= 32; msk <<= 1) {
        o.x += __shfl_xor(o.x, msk);
        o.y += __shfl_xor(o.y, msk);
        o.z += __shfl_xor(o.z, msk);
        o.w += __shfl_xor(o.w, msk);
    }

    // ---- residual + store (lanes 0..7 write 128B contiguous) ----
    if (g == 0) {
        const float4 ci = *(const float4*)(cie + tile * D + d0);
        float4 r = make_float4(o.x + ci.x, o.y + ci.y, o.z + ci.z, o.w + ci.w);
        *(float4*)(out + tile * D + d0) = r;
    }
}

extern "C" void kernel_launch(void* const* d_in, const int* in_sizes, int n_in,
                              void* d_out, int out_size, void* d_ws, size_t ws_size,
                              hipStream_t stream) {
    const float* cu   = (const float*)d_in[0];
    const float* sue  = (const float*)d_in[1];
    const float* cie  = (const float*)d_in[2];
    const int*   mask = (const int*)d_in[3];
    float* out = (float*)d_out;

    // 4 tiles (waves) per 256-thread block; TILES = 102400 divisible by 4.
    DIB_69861938037647_kernel<<<TILES / 4, 256, 0, stream>>>(cu, sue, cie, mask, out);
}